// Round 11
// baseline (425.477 us; speedup 1.0000x reference)
//
#include <hip/hip_runtime.h>
#include <hip/hip_bf16.h>

#define HID 128
#define NN 50000
#define NR 500
#define NE 625000
#define LRELU 0.01f
#define SCAN_BLOCKS 196   // ceil(NN/256)
#define NBLK_SC 256       // fixed grid for count/scatter (deterministic per-block edge sets)

typedef __hip_bfloat16 bf16;
typedef __attribute__((ext_vector_type(8))) short short8;
typedef __attribute__((ext_vector_type(4))) float float4_;

__device__ __forceinline__ float b2f(bf16 v) { return __bfloat162float(v); }
__device__ __forceinline__ bf16 f2b(float v) { return __float2bfloat16(v); }

__device__ __forceinline__ float san(float v) {
    return (v == v && v > -1e30f && v < 1e30f) ? v : 0.f;
}

// fast tanh: 1 - 2/(e^{2x}+1)
__device__ __forceinline__ float ftanh(float a) {
    float e = __expf(2.f * a);
    return 1.f - 2.f * __builtin_amdgcn_rcpf(e + 1.f);
}

__device__ __forceinline__ float ldf(const void* p, int i, int f32) {
    return f32 ? ((const float*)p)[i] : b2f(((const bf16*)p)[i]);
}
__device__ __forceinline__ void stf(void* p, int i, float v, int f32) {
    if (f32) ((float*)p)[i] = v;
    else ((bf16*)p)[i] = f2b(v);
}

__device__ __forceinline__ int clampi(int v, int hi) {
    return v < 0 ? 0 : (v >= hi ? hi - 1 : v);
}
__device__ __forceinline__ int idx_at(const int* p, int i, int is64) {
    return p[is64 ? (2 * i) : i];
}

__device__ __forceinline__ unsigned short bfbits(float v) {
    bf16 h = f2b(v);
    return *(unsigned short*)&h;
}
__device__ __forceinline__ unsigned int packbf2(float a, float b) {
    return (unsigned int)bfbits(a) | ((unsigned int)bfbits(b) << 16);
}
__device__ __forceinline__ float bflo(unsigned int u) { return __uint_as_float(u << 16); }
__device__ __forceinline__ float bfhi(unsigned int u) { return __uint_as_float(u & 0xffff0000u); }

__device__ __forceinline__ float xorReduce16(float v) {
    v += __shfl_xor(v, 1, 64);
    v += __shfl_xor(v, 2, 64);
    v += __shfl_xor(v, 4, 64);
    v += __shfl_xor(v, 8, 64);
    return v;
}
__device__ __forceinline__ float waveMax(float v) {
#pragma unroll
    for (int o = 1; o < 64; o <<= 1) v = fmaxf(v, __shfl_xor(v, o, 64));
    return v;
}
__device__ __forceinline__ float waveSum(float v) {
#pragma unroll
    for (int o = 1; o < 64; o <<= 1) v += __shfl_xor(v, o, 64);
    return v;
}

// 8-wide dot of W[row][col..col+8) with vec[0..8); W row stride = 2*HID
__device__ __forceinline__ float dot8(const void* W, int row, int col, int f32,
                                      const float* vec) {
    float s;
    if (f32) {
        const float* p = (const float*)W + (size_t)row * 2 * HID + col;
        float4 a = *(const float4*)p;
        float4 b = *(const float4*)(p + 4);
        s = a.x * vec[0] + a.y * vec[1] + a.z * vec[2] + a.w * vec[3]
          + b.x * vec[4] + b.y * vec[5] + b.z * vec[6] + b.w * vec[7];
    } else {
        short8 v = *(const short8*)((const bf16*)W + (size_t)row * 2 * HID + col);
        s = 0.f;
#pragma unroll
        for (int i = 0; i < 8; ++i) {
            unsigned int u = ((unsigned int)(unsigned short)v[i]) << 16;
            s += __uint_as_float(u) * vec[i];
        }
    }
    return s;
}

__device__ __forceinline__ int octant_of(int head) {
    return (head * 8) / NN;   // head < 50000 -> 0..7
}

// ---------------------------------------------------------------- consolidated dtype detect
struct DetectArr {
    const void* p[16];
    int sz[16];
    int kind[16];
};

__global__ void detect_all(DetectArr d, int* __restrict__ flags) {
    int b = blockIdx.x;
    int t = threadIdx.x;
    if (d.kind[b] == 1) {
        if (t < 64) {
            const int* q = (const int*)d.p[b];
            int o = q[2 * t + 1];
            unsigned long long bm = __ballot(o != 0);
            if (t == 0) flags[b] = (bm == 0ull) ? 1 : 0;
        }
        return;
    }
    __shared__ int sb[256], sf[256];
    const unsigned int* w = (const unsigned int*)d.p[b];
    int K = d.sz[b] >> 1;
    if (K > 4096) K = 4096;
    int bv = 0, fv = 0;
    for (int i = t; i < K; i += 256) {
        unsigned int x = w[i];
        unsigned int lo = x & 0xFFFFu, hi = x >> 16;
        if (lo == 0u) {
            if (hi) fv++;
        } else {
            unsigned int e = (lo >> 7) & 0xFFu;
            if (e >= 90u && e <= 160u) bv++;
            else fv++;
        }
    }
    sb[t] = bv; sf[t] = fv;
    __syncthreads();
    for (int o = 128; o > 0; o >>= 1) {
        if (t < o) { sb[t] += sb[t + o]; sf[t] += sf[t + o]; }
        __syncthreads();
    }
    if (t == 0) flags[b] = (sf[0] > sb[0]) ? 1 : 0;
}

// ---------------------------------------------------------------- BatchNorm: stats
__global__ void bn_stats(const void* __restrict__ r, const int* __restrict__ flags,
                         float* __restrict__ stats) {
    __shared__ float sb[256], sq[256];
    const int fr = flags[1];
    int h = blockIdx.x;
    int t = threadIdx.x;
    float s = 0.f, ss = 0.f;
    for (int i = t; i < NR; i += 256) {
        float v = ldf(r, i * HID + h, fr);
        s += v; ss += v * v;
    }
    sb[t] = s; sq[t] = ss;
    __syncthreads();
    for (int o = 128; o > 0; o >>= 1) {
        if (t < o) { sb[t] += sb[t + o]; sq[t] += sq[t + o]; }
        __syncthreads();
    }
    if (t == 0) {
        float mu = sb[0] / NR;
        float var = sq[0] / NR - mu * mu;
        if (var < 0.f) var = 0.f;
        stats[h] = mu;
        stats[HID + h] = rsqrtf(var + 1e-5f);
    }
}

// ---------------------------------------------------------------- BatchNorm: apply
__global__ void bn_apply(const void* __restrict__ r, const void* __restrict__ gamma,
                         const void* __restrict__ beta, const int* __restrict__ flags,
                         const float* __restrict__ stats,
                         float* __restrict__ rnorm, void* __restrict__ out_base) {
    const int fr = flags[1], fg = flags[14], fb = flags[15], fo = flags[0];
    int i = blockIdx.x * 256 + threadIdx.x;
    if (i >= NR * HID) return;
    int h = i & 127;
    float v = san((ldf(r, i, fr) - stats[h]) * stats[HID + h] * ldf(gamma, h, fg)
                  + ldf(beta, h, fb));
    rnorm[i] = v;
    stf(out_base, NN * HID + i, v, fo);
}

// ---------------------------------------------------------------- edge-constant vectors
__global__ void precomp_kernel(const void* __restrict__ Wmatt, const void* __restrict__ bmatt,
                               const void* __restrict__ qc,
                               const void* __restrict__ Wxatt, const void* __restrict__ bxatt,
                               const void* __restrict__ fq, const int* __restrict__ flags,
                               float* __restrict__ cmatt, float* __restrict__ cxatt) {
    __shared__ float vs[HID];
    __shared__ float part[256];
    const void* W    = blockIdx.x ? Wxatt : Wmatt;
    const void* bias = blockIdx.x ? bxatt : bmatt;
    const void* vsrc = blockIdx.x ? fq : qc;
    float* out       = blockIdx.x ? cxatt : cmatt;
    const int fW = flags[blockIdx.x ? 11 : 8];
    const int fb = flags[blockIdx.x ? 12 : 9];
    const int fv = flags[blockIdx.x ? 3 : 2];
    int t = threadIdx.x;
    if (t < HID) vs[t] = ldf(vsrc, t, fv);
    __syncthreads();
    int h = t & 127, ks = t >> 7;
    float a = 0.f;
#pragma unroll
    for (int i = 0; i < 8; ++i)
        a += dot8(W, h, HID + ks * 64 + i * 8, fW, &vs[ks * 64 + i * 8]);
    part[t] = a;
    __syncthreads();
    if (t < HID) out[h] = san(part[h] + part[h + 128] + ldf(bias, h, fb));
}

// ---------------------------------------------------------------- Rmb[rel,h] (bf16), 2 rels/block
__global__ void rm_kernel(const void* __restrict__ Wmess, const void* __restrict__ bmess,
                          const int* __restrict__ flags,
                          const float* __restrict__ rnorm, bf16* __restrict__ Rmb) {
    __shared__ float rl[2][HID];
    const int fW = flags[6], fb = flags[7];
    int t = threadIdx.x;
    int sub = t >> 7, h = t & 127;
    int rel = blockIdx.x * 2 + sub;
    rl[sub][h] = rnorm[rel * HID + h];
    __syncthreads();
    float a = ldf(bmess, h, fb);
#pragma unroll
    for (int i = 0; i < 16; ++i)
        a += dot8(Wmess, h, HID + i * 8, fW, &rl[sub][i * 8]);
    Rmb[rel * HID + h] = f2b(san(a));
}

// ================================================================ MFMA kernels
#define MLDA 136

__device__ __forceinline__ short8 load_bfrag(const void* W, int n, int k0, int f32) {
    short8 b;
    if (f32) {
        const float* Wf = (const float*)W + (size_t)n * 2 * HID + k0;
        float4 u0 = *(const float4*)Wf;
        float4 u1 = *(const float4*)(Wf + 4);
        b[0] = (short)bfbits(u0.x); b[1] = (short)bfbits(u0.y);
        b[2] = (short)bfbits(u0.z); b[3] = (short)bfbits(u0.w);
        b[4] = (short)bfbits(u1.x); b[5] = (short)bfbits(u1.y);
        b[6] = (short)bfbits(u1.z); b[7] = (short)bfbits(u1.w);
    } else {
        b = *(const short8*)((const bf16*)W + (size_t)n * 2 * HID + k0);
    }
    return b;
}

// ---------------------------------------------------------------- Xm = x @ Wmess[:, :128]^T
__global__ __launch_bounds__(256, 4) void xm_mfma(const void* __restrict__ x,
                                                  const void* __restrict__ Wmess,
                                                  const int* __restrict__ flags,
                                                  bf16* __restrict__ Xmb) {
    __shared__ short ml[64 * MLDA];
    const int fx = flags[0], fW = flags[6];
    int tid = threadIdx.x;
    int l = tid & 63, w = tid >> 6;
    int quad = l >> 4, lo16 = l & 15;
    int nbase = w * 32;
    short8 bfr[2][4];
#pragma unroll
    for (int nt = 0; nt < 2; ++nt)
#pragma unroll
        for (int kk = 0; kk < 4; ++kk)
            bfr[nt][kk] = load_bfrag(Wmess, nbase + nt * 16 + lo16, kk * 32 + quad * 8, fW);

    const int ntiles = (NN + 63) / 64;
    for (int tile = blockIdx.x; tile < ntiles; tile += gridDim.x) {
        __syncthreads();
#pragma unroll
        for (int p = 0; p < 8; ++p) {
            int rl_ = p * 8 + (tid >> 5);
            int node = clampi(tile * 64 + rl_, NN);
            int k4 = (tid & 31) * 4;
            unsigned int o0, o1;
            if (fx) {
                float4 v = *(const float4*)((const float*)x + (size_t)node * HID + k4);
                o0 = packbf2(v.x, v.y);
                o1 = packbf2(v.z, v.w);
            } else {
                uint2 u = *(const uint2*)((const bf16*)x + (size_t)node * HID + k4);
                o0 = u.x; o1 = u.y;
            }
            unsigned int* dst = (unsigned int*)&ml[rl_ * MLDA + k4];
            dst[0] = o0; dst[1] = o1;
        }
        __syncthreads();
        float4_ acc[4][2];
#pragma unroll
        for (int mt = 0; mt < 4; ++mt)
#pragma unroll
            for (int nt = 0; nt < 2; ++nt)
                acc[mt][nt] = (float4_){0.f, 0.f, 0.f, 0.f};
#pragma unroll
        for (int kk = 0; kk < 4; ++kk) {
            short8 a[4];
#pragma unroll
            for (int mt = 0; mt < 4; ++mt)
                a[mt] = *(const short8*)&ml[(mt * 16 + lo16) * MLDA + kk * 32 + quad * 8];
#pragma unroll
            for (int mt = 0; mt < 4; ++mt)
#pragma unroll
                for (int nt = 0; nt < 2; ++nt)
                    acc[mt][nt] = __builtin_amdgcn_mfma_f32_16x16x32_bf16(
                        a[mt], bfr[nt][kk], acc[mt][nt], 0, 0, 0);
        }
#pragma unroll
        for (int mt = 0; mt < 4; ++mt)
#pragma unroll
            for (int nt = 0; nt < 2; ++nt)
#pragma unroll
                for (int r = 0; r < 4; ++r) {
                    int node = tile * 64 + mt * 16 + quad * 4 + r;
                    if (node < NN)
                        Xmb[node * HID + nbase + nt * 16 + lo16] = f2b(san(acc[mt][nt][r]));
                }
    }
}

// ---------------------------------------------------------------- edge logits: OCTANT + 8 blocks/CU
// Octant pinning verified (R10): FETCH 230->164MB. Kernel is NOT fetch-bound — VALU 48% +
// latency stalls at 58% occupancy. With octant-bounded working set (1.6MB/XCD regardless of
// block count), raising occupancy no longer triggers R2's thrash mechanism: 8 blocks/CU to
// hide gather latency. LDS 18432B x 8 = 147K <= 160K.
__global__ __launch_bounds__(256, 8) void edge_coeff_mfma(
        const bf16* __restrict__ Xmb, const bf16* __restrict__ Rmb,
        const void* __restrict__ Wmatt, const float* __restrict__ cmatt,
        const void* __restrict__ maw, const unsigned int* __restrict__ ohr,
        const int* __restrict__ oslot, const int* __restrict__ ooffs,
        const int* __restrict__ flags, float* __restrict__ ccsr) {
    __shared__ short ml[64 * MLDA];
    __shared__ float swave[4][64];
    const int fWm = flags[8], fmw = flags[10];
    int tid = threadIdx.x;
    int l = tid & 63, w = tid >> 6;
    int quad = l >> 4, lo16 = l & 15;
    int nbase = w * 32;
    short8 bfr[2][4];
#pragma unroll
    for (int nt = 0; nt < 2; ++nt)
#pragma unroll
        for (int kk = 0; kk < 4; ++kk)
            bfr[nt][kk] = load_bfrag(Wmatt, nbase + nt * 16 + lo16, kk * 32 + quad * 8, fWm);

    int n0 = nbase + lo16, n1 = n0 + 16;
    float c0 = cmatt[n0], c1 = cmatt[n1];
    float w0 = ldf(maw, n0, fmw), w1 = ldf(maw, n1, fmw);

    const int k = blockIdx.x & 7;
    const int beg = ooffs[k], end = ooffs[k + 1];
    const int tstride = gridDim.x >> 3;
    const int seg = tid & 15;
    const int rowsub = tid >> 4;

    for (int t = blockIdx.x >> 3;; t += tstride) {
        int base = beg + t * 64;
        if (base >= end) break;
        __syncthreads();
#pragma unroll
        for (int p = 0; p < 4; ++p) {
            int el = p * 16 + rowsub;
            int i = base + el;
            int idx = i < end ? i : end - 1;
            unsigned int hr = ohr[idx];
            int head = hr & 0xffffu, rel = hr >> 16;
            int k8 = seg * 8;
            uint4 xv = *(const uint4*)&Xmb[head * HID + k8];
            uint4 rv = *(const uint4*)&Rmb[rel * HID + k8];
            uint4 o;
            o.x = packbf2(ftanh(bflo(xv.x) + bflo(rv.x)), ftanh(bfhi(xv.x) + bfhi(rv.x)));
            o.y = packbf2(ftanh(bflo(xv.y) + bflo(rv.y)), ftanh(bfhi(xv.y) + bfhi(rv.y)));
            o.z = packbf2(ftanh(bflo(xv.z) + bflo(rv.z)), ftanh(bfhi(xv.z) + bfhi(rv.z)));
            o.w = packbf2(ftanh(bflo(xv.w) + bflo(rv.w)), ftanh(bfhi(xv.w) + bfhi(rv.w)));
            *(uint4*)&ml[el * MLDA + k8] = o;
        }
        __syncthreads();
        float4_ acc[4][2];
#pragma unroll
        for (int mt = 0; mt < 4; ++mt)
#pragma unroll
            for (int nt = 0; nt < 2; ++nt)
                acc[mt][nt] = (float4_){0.f, 0.f, 0.f, 0.f};
#pragma unroll
        for (int kk = 0; kk < 4; ++kk) {
            short8 a[4];
#pragma unroll
            for (int mt = 0; mt < 4; ++mt)
                a[mt] = *(const short8*)&ml[(mt * 16 + lo16) * MLDA + kk * 32 + quad * 8];
#pragma unroll
            for (int mt = 0; mt < 4; ++mt)
#pragma unroll
                for (int nt = 0; nt < 2; ++nt)
                    acc[mt][nt] = __builtin_amdgcn_mfma_f32_16x16x32_bf16(
                        a[mt], bfr[nt][kk], acc[mt][nt], 0, 0, 0);
        }
#pragma unroll
        for (int mt = 0; mt < 4; ++mt)
#pragma unroll
            for (int r = 0; r < 4; ++r) {
                float z0 = acc[mt][0][r] + c0;
                z0 = z0 > 0.f ? z0 : LRELU * z0;
                float z1 = acc[mt][1][r] + c1;
                z1 = z1 > 0.f ? z1 : LRELU * z1;
                float s = w0 * z0 + w1 * z1;
                s = xorReduce16(s);
                if (lo16 == 0) swave[w][mt * 16 + quad * 4 + r] = s;
            }
        __syncthreads();
        if (tid < 64) {
            int i = base + tid;
            if (i < end)
                ccsr[oslot[i]] = san(swave[0][tid] + swave[1][tid]
                                     + swave[2][tid] + swave[3][tid]);
        }
    }
}

// ---------------------------------------------------------------- gate
__global__ __launch_bounds__(256, 4) void gate_mfma(
        const void* __restrict__ x, const bf16* __restrict__ smb,
        const void* __restrict__ Wxatt, const float* __restrict__ cxatt,
        const void* __restrict__ xaw, const int* __restrict__ flags,
        void* __restrict__ outx) {
    __shared__ short ml[64 * MLDA];
    __shared__ float swave[4][64];
    __shared__ float lgL[64];
    const int fx = flags[0], fWx = flags[11], fxw = flags[13], fo = flags[0];
    int tid = threadIdx.x;
    int l = tid & 63, w = tid >> 6;
    int quad = l >> 4, lo16 = l & 15;
    int nbase = w * 32;
    short8 bfr[2][4];
#pragma unroll
    for (int nt = 0; nt < 2; ++nt)
#pragma unroll
        for (int kk = 0; kk < 4; ++kk)
            bfr[nt][kk] = load_bfrag(Wxatt, nbase + nt * 16 + lo16, kk * 32 + quad * 8, fWx);

    int n0 = nbase + lo16, n1 = n0 + 16;
    float c0 = cxatt[n0], c1 = cxatt[n1];
    float w0 = ldf(xaw, n0, fxw), w1 = ldf(xaw, n1, fxw);

    const int ntiles = (NN + 31) / 32;
    for (int tile = blockIdx.x; tile < ntiles; tile += gridDim.x) {
        __syncthreads();
#pragma unroll
        for (int p = 0; p < 8; ++p) {
            int rl_ = p * 8 + (tid >> 5);
            int node = clampi(tile * 32 + (rl_ >> 1), NN);
            int k4 = (tid & 31) * 4;
            unsigned int o0, o1;
            if (rl_ & 1) {
                uint2 u = *(const uint2*)&smb[node * HID + k4];
                o0 = u.x; o1 = u.y;
            } else if (fx) {
                float4 v = *(const float4*)((const float*)x + (size_t)node * HID + k4);
                o0 = packbf2(v.x, v.y);
                o1 = packbf2(v.z, v.w);
            } else {
                uint2 u = *(const uint2*)((const bf16*)x + (size_t)node * HID + k4);
                o0 = u.x; o1 = u.y;
            }
            unsigned int* dst = (unsigned int*)&ml[rl_ * MLDA + k4];
            dst[0] = o0; dst[1] = o1;
        }
        __syncthreads();
        float4_ acc[4][2];
#pragma unroll
        for (int mt = 0; mt < 4; ++mt)
#pragma unroll
            for (int nt = 0; nt < 2; ++nt)
                acc[mt][nt] = (float4_){0.f, 0.f, 0.f, 0.f};
#pragma unroll
        for (int kk = 0; kk < 4; ++kk) {
            short8 a[4];
#pragma unroll
            for (int mt = 0; mt < 4; ++mt)
                a[mt] = *(const short8*)&ml[(mt * 16 + lo16) * MLDA + kk * 32 + quad * 8];
#pragma unroll
            for (int mt = 0; mt < 4; ++mt)
#pragma unroll
                for (int nt = 0; nt < 2; ++nt)
                    acc[mt][nt] = __builtin_amdgcn_mfma_f32_16x16x32_bf16(
                        a[mt], bfr[nt][kk], acc[mt][nt], 0, 0, 0);
        }
#pragma unroll
        for (int mt = 0; mt < 4; ++mt)
#pragma unroll
            for (int r = 0; r < 4; ++r) {
                float z0 = acc[mt][0][r] + c0;
                z0 = z0 > 0.f ? z0 : LRELU * z0;
                float z1 = acc[mt][1][r] + c1;
                z1 = z1 > 0.f ? z1 : LRELU * z1;
                float s = w0 * z0 + w1 * z1;
                s = xorReduce16(s);
                if (lo16 == 0) swave[w][mt * 16 + quad * 4 + r] = s;
            }
        __syncthreads();
        if (tid < 64)
            lgL[tid] = san(swave[0][tid] + swave[1][tid] + swave[2][tid] + swave[3][tid]);
        __syncthreads();
#pragma unroll
        for (int it = 0; it < 16; ++it) {
            int idx = tid + 256 * it;
            int nl = idx >> 7, h = idx & 127;
            int node = tile * 32 + nl;
            if (node < NN) {
                float g0 = lgL[2 * nl], g1 = lgL[2 * nl + 1];
                float mm = fmaxf(g0, g1);
                float e0 = __expf(g0 - mm), e1 = __expf(g1 - mm);
                float inv = __builtin_amdgcn_rcpf(e0 + e1);
                float xv = ldf(x, node * HID + h, fx);
                float sv = b2f(smb[node * HID + h]);
                stf(outx, node * HID + h, san((e0 * xv + e1 * sv) * inv), fo);
            }
        }
    }
}

// ---------------------------------------------------------------- CSR build (R6 form: verified)
__global__ void count_kernel(const int* __restrict__ ei, const int* __restrict__ flags,
                             int* __restrict__ counts, int* __restrict__ blockOct) {
    __shared__ int oh[8];
    const int is64e = flags[4];
    if (threadIdx.x < 8) oh[threadIdx.x] = 0;
    __syncthreads();
    for (int e = blockIdx.x * blockDim.x + threadIdx.x; e < NE; e += gridDim.x * blockDim.x) {
        int tail = clampi(idx_at(ei, NE + e, is64e), NN);
        int head = clampi(idx_at(ei, e, is64e), NN);
        atomicAdd(&counts[tail], 1);
        atomicAdd(&oh[octant_of(head)], 1);   // LDS atomic
    }
    __syncthreads();
    if (threadIdx.x < 8) blockOct[blockIdx.x * 8 + threadIdx.x] = oh[threadIdx.x];
}

__global__ void scan_phase1(const int* __restrict__ counts, int* __restrict__ offs,
                            int* __restrict__ bsum) {
    __shared__ int buf[256];
    int t = threadIdx.x;
    int i = blockIdx.x * 256 + t;
    int v = (i < NN) ? counts[i] : 0;
    buf[t] = v;
    __syncthreads();
    for (int off = 1; off < 256; off <<= 1) {
        int add = (t >= off) ? buf[t - off] : 0;
        __syncthreads();
        buf[t] += add;
        __syncthreads();
    }
    if (i < NN) offs[i] = buf[t] - v;
    if (t == 255) bsum[blockIdx.x] = buf[255];
}

__global__ void scan_phase2(int* __restrict__ bsum, int* __restrict__ bexc) {
    __shared__ int buf[256];
    int t = threadIdx.x;
    int v = (t < SCAN_BLOCKS) ? bsum[t] : 0;
    buf[t] = v;
    __syncthreads();
    for (int off = 1; off < 256; off <<= 1) {
        int add = (t >= off) ? buf[t - off] : 0;
        __syncthreads();
        buf[t] += add;
        __syncthreads();
    }
    if (t < SCAN_BLOCKS) bexc[t] = buf[t] - v;
    if (t == 255) bexc[SCAN_BLOCKS] = buf[255];
}

__global__ void scan_phase3(int* __restrict__ offs, int* __restrict__ cursor,
                            const int* __restrict__ bexc) {
    int i = blockIdx.x * 256 + threadIdx.x;
    if (i < NN) {
        int v = offs[i] + bexc[blockIdx.x];
        offs[i] = v;
        cursor[i] = v;
    }
    if (i == 0) offs[NN] = bexc[SCAN_BLOCKS];
}

// scan blockOct[NBLK_SC][8] -> blockBase[NBLK_SC][8] (exclusive, octant-major) + ooffs[9]
__global__ void oct_scan(const int* __restrict__ blockOct, int* __restrict__ ooffs,
                         int* __restrict__ blockBase) {
    __shared__ int buf[256];
    __shared__ int excl[256][8];
    __shared__ int octTot[8], octBase[9];
    int t = threadIdx.x;
#pragma unroll
    for (int oo = 0; oo < 8; ++oo) {
        int v = blockOct[t * 8 + oo];
        buf[t] = v;
        __syncthreads();
        for (int off = 1; off < 256; off <<= 1) {
            int add = (t >= off) ? buf[t - off] : 0;
            __syncthreads();
            buf[t] += add;
            __syncthreads();
        }
        excl[t][oo] = buf[t] - v;
        if (t == 255) octTot[oo] = buf[255];
        __syncthreads();
    }
    if (t == 0) {
        int acc = 0;
        for (int oo = 0; oo < 8; ++oo) { octBase[oo] = acc; acc += octTot[oo]; }
        octBase[8] = acc;
        for (int i = 0; i < 9; ++i) ooffs[i] = octBase[i];
    }
    __syncthreads();
#pragma unroll
    for (int oo = 0; oo < 8; ++oo)
        blockBase[t * 8 + oo] = excl[t][oo] + octBase[oo];
}

// scatter: tail-CSR (global cursorT atomics) + octant list via LDS cursors seeded from
// blockBase — zero global-atomic contention. Same grid/stride as count_kernel (required).
__global__ void scatter_kernel(const int* __restrict__ ei, const int* __restrict__ ea,
                               const int* __restrict__ flags,
                               int* __restrict__ cursorT, const int* __restrict__ blockBase,
                               unsigned int* __restrict__ hrcsr,
                               unsigned int* __restrict__ ohr, int* __restrict__ oslot) {
    __shared__ int cur[8];
    const int is64e = flags[4], is64a = flags[5];
    if (threadIdx.x < 8) cur[threadIdx.x] = blockBase[blockIdx.x * 8 + threadIdx.x];
    __syncthreads();
    for (int e = blockIdx.x * blockDim.x + threadIdx.x; e < NE; e += gridDim.x * blockDim.x) {
        int tail = clampi(idx_at(ei, NE + e, is64e), NN);
        int head = clampi(idx_at(ei, e, is64e), NN);
        int rel = clampi(idx_at(ea, e, is64a), NR);
        unsigned int hr = (unsigned int)head | ((unsigned int)rel << 16);
        int p = atomicAdd(&cursorT[tail], 1);
        if (p >= 0 && p < NE) hrcsr[p] = hr;
        int q = atomicAdd(&cur[octant_of(head)], 1);   // LDS atomic
        if (q >= 0 && q < NE) {
            ohr[q] = hr;
            oslot[q] = (p >= 0 && p < NE) ? p : 0;
        }
    }
}

// ---------------------------------------------------------------- node softmax + aggregation
__global__ __launch_bounds__(256, 8) void node_aggr_kernel(
        const bf16* __restrict__ Xmb, const bf16* __restrict__ Rmb,
        const int* __restrict__ offs, const unsigned int* __restrict__ hrcsr,
        const float* __restrict__ ccsr, bf16* __restrict__ smb) {
    int tid = threadIdx.x;
    int sub = tid >> 6;
    int lane = tid & 63;
    int node = blockIdx.x * 4 + sub;
    if (node >= NN) return;
    int s = offs[node], en = offs[node + 1];

    float m = -INFINITY;
    for (int i = s + lane; i < en; i += 64) m = fmaxf(m, ccsr[i]);
    m = waveMax(m);
    float lsum = 0.f;
    for (int i = s + lane; i < en; i += 64) lsum += __expf(ccsr[i] - m);
    lsum = waveSum(lsum);
    float inv = 1.f / (lsum + 1e-16f);

    const int col = lane * 2;
    float acc0 = 0.f, acc1 = 0.f;
    int i = s;
    for (; i + 2 <= en; i += 2) {
        unsigned int hr0 = hrcsr[i], hr1 = hrcsr[i + 1];
        float wg0 = __expf(ccsr[i] - m), wg1 = __expf(ccsr[i + 1] - m);
        unsigned int xv0 = *(const unsigned int*)&Xmb[(hr0 & 0xffffu) * HID + col];
        unsigned int rv0 = *(const unsigned int*)&Rmb[(hr0 >> 16) * HID + col];
        unsigned int xv1 = *(const unsigned int*)&Xmb[(hr1 & 0xffffu) * HID + col];
        unsigned int rv1 = *(const unsigned int*)&Rmb[(hr1 >> 16) * HID + col];
        acc0 += wg0 * ftanh(bflo(xv0) + bflo(rv0)) + wg1 * ftanh(bflo(xv1) + bflo(rv1));
        acc1 += wg0 * ftanh(bfhi(xv0) + bfhi(rv0)) + wg1 * ftanh(bfhi(xv1) + bfhi(rv1));
    }
    if (i < en) {
        unsigned int hr0 = hrcsr[i];
        float wg0 = __expf(ccsr[i] - m);
        unsigned int xv0 = *(const unsigned int*)&Xmb[(hr0 & 0xffffu) * HID + col];
        unsigned int rv0 = *(const unsigned int*)&Rmb[(hr0 >> 16) * HID + col];
        acc0 += wg0 * ftanh(bflo(xv0) + bflo(rv0));
        acc1 += wg0 * ftanh(bfhi(xv0) + bfhi(rv0));
    }
    *(unsigned int*)&smb[node * HID + col] = packbf2(san(acc0 * inv), san(acc1 * inv));
}

extern "C" void kernel_launch(void* const* d_in, const int* in_sizes, int n_in,
                              void* d_out, int out_size, void* d_ws, size_t ws_size,
                              hipStream_t stream) {
    const void* x     = d_in[0];
    const void* r     = d_in[1];
    const void* qc    = d_in[2];
    const void* fq    = d_in[3];
    const int*  ei    = (const int*)d_in[4];
    const int*  ea    = (const int*)d_in[5];
    const void* Wmess = d_in[6];
    const void* bmess = d_in[7];
    const void* Wmatt = d_in[8];
    const void* bmatt = d_in[9];
    const void* maw   = d_in[10];
    const void* Wxatt = d_in[11];
    const void* bxatt = d_in[12];
    const void* xaw   = d_in[13];
    const void* gamma = d_in[14];
    const void* beta  = d_in[15];

    char* base = (char*)d_ws;
    size_t off = 0;
    auto alloc = [&](size_t bytes, size_t align) -> size_t {
        off = (off + align - 1) & ~(align - 1);
        size_t cur = off; off += bytes; return cur;
    };
    size_t o_flags  = alloc(16 * 4, 4);
    size_t o_counts = alloc((size_t)NN * 4, 4);
    size_t o_offs   = alloc((size_t)(NN + 1) * 4, 4);
    size_t o_cursor = alloc((size_t)(NN + 3) * 4, 4);
    size_t o_bsum   = alloc(256 * 4, 4);
    size_t o_bexc   = alloc(264 * 4, 4);
    size_t o_bOct   = alloc((size_t)NBLK_SC * 8 * 4, 4);
    size_t o_bBase  = alloc((size_t)NBLK_SC * 8 * 4, 4);
    size_t o_ooffs  = alloc(9 * 4, 4);
    size_t o_hrcsr  = alloc((size_t)NE * 4, 4);
    size_t o_ohr    = alloc((size_t)NE * 4, 4);
    size_t o_oslot  = alloc((size_t)NE * 4, 4);
    size_t o_ccsr   = alloc((size_t)NE * 4, 4);
    size_t o_rnorm  = alloc((size_t)NR * HID * 4, 4);
    size_t o_stats  = alloc(2 * HID * 4, 4);
    size_t o_cmatt  = alloc(HID * 4, 4);
    size_t o_cxatt  = alloc(HID * 4, 4);
    size_t o_Rmb    = alloc((size_t)NR * HID * 2, 4);
    size_t o_Xmb    = alloc((size_t)NN * HID * 2, 4);
    size_t o_smb    = alloc((size_t)NN * HID * 2, 4);

    int*          flags     = (int*)(base + o_flags);
    int*          counts    = (int*)(base + o_counts);
    int*          offs      = (int*)(base + o_offs);
    int*          cursor    = (int*)(base + o_cursor);
    int*          bsum      = (int*)(base + o_bsum);
    int*          bexc      = (int*)(base + o_bexc);
    int*          blockOct  = (int*)(base + o_bOct);
    int*          blockBase = (int*)(base + o_bBase);
    int*          ooffs     = (int*)(base + o_ooffs);
    unsigned int* hrcsr     = (unsigned int*)(base + o_hrcsr);
    unsigned int* ohr       = (unsigned int*)(base + o_ohr);
    int*          oslot     = (int*)(base + o_oslot);
    float*        ccsr      = (float*)(base + o_ccsr);
    float*        rnorm     = (float*)(base + o_rnorm);
    float*        stats     = (float*)(base + o_stats);
    float*        cmatt     = (float*)(base + o_cmatt);
    float*        cxatt     = (float*)(base + o_cxatt);
    bf16*         Rmb       = (bf16*)(base + o_Rmb);
    bf16*         Xmb       = (bf16*)(base + o_Xmb);
    bf16*         smb       = (bf16*)(base + o_smb);

    hipMemsetAsync(counts, 0, (size_t)NN * sizeof(int), stream);

    DetectArr da;
    const void* ps[16] = {x, r, qc, fq, ei, ea, Wmess, bmess, Wmatt, bmatt, maw,
                          Wxatt, bxatt, xaw, gamma, beta};
    int szs[16] = {NN * HID, NR * HID, HID, HID, 2 * NE, NE, 2 * HID * HID, HID,
                   2 * HID * HID, HID, HID, 2 * HID * HID, HID, HID, HID, HID};
    for (int i = 0; i < 16; ++i) {
        da.p[i] = ps[i];
        da.sz[i] = szs[i];
        da.kind[i] = (i == 4 || i == 5) ? 1 : 0;
    }
    detect_all<<<16, 256, 0, stream>>>(da, flags);

    bn_stats<<<HID, 256, 0, stream>>>(r, flags, stats);
    bn_apply<<<(NR * HID + 255) / 256, 256, 0, stream>>>(r, gamma, beta, flags, stats,
                                                         rnorm, d_out);
    precomp_kernel<<<2, 256, 0, stream>>>(Wmatt, bmatt, qc, Wxatt, bxatt, fq, flags,
                                          cmatt, cxatt);
    rm_kernel<<<NR / 2, 256, 0, stream>>>(Wmess, bmess, flags, rnorm, Rmb);
    xm_mfma<<<782, 256, 0, stream>>>(x, Wmess, flags, Xmb);
    count_kernel<<<NBLK_SC, 256, 0, stream>>>(ei, flags, counts, blockOct);
    scan_phase1<<<SCAN_BLOCKS, 256, 0, stream>>>(counts, offs, bsum);
    scan_phase2<<<1, 256, 0, stream>>>(bsum, bexc);
    scan_phase3<<<SCAN_BLOCKS, 256, 0, stream>>>(offs, cursor, bexc);
    oct_scan<<<1, 256, 0, stream>>>(blockOct, ooffs, blockBase);
    scatter_kernel<<<NBLK_SC, 256, 0, stream>>>(ei, ea, flags, cursor, blockBase,
                                                hrcsr, ohr, oslot);
    edge_coeff_mfma<<<2048, 256, 0, stream>>>(Xmb, Rmb, Wmatt, cmatt, maw, ohr, oslot,
                                              ooffs, flags, ccsr);
    node_aggr_kernel<<<(NN + 3) / 4, 256, 0, stream>>>(Xmb, Rmb, offs, hrcsr, ccsr, smb);
    gate_mfma<<<1563, 256, 0, stream>>>(x, smb, Wxatt, cxatt, xaw, flags, d_out);
}

// Round 12
// 401.840 us; speedup vs baseline: 1.0588x; 1.0588x over previous
//
#include <hip/hip_runtime.h>
#include <hip/hip_bf16.h>

#define HID 128
#define NN 50000
#define NR 500
#define NE 625000
#define LRELU 0.01f
#define SCAN_BLOCKS 196   // ceil(NN/256)

typedef __hip_bfloat16 bf16;
typedef __attribute__((ext_vector_type(8))) short short8;
typedef __attribute__((ext_vector_type(4))) float float4_;

__device__ __forceinline__ float b2f(bf16 v) { return __bfloat162float(v); }
__device__ __forceinline__ bf16 f2b(float v) { return __float2bfloat16(v); }

__device__ __forceinline__ float san(float v) {
    return (v == v && v > -1e30f && v < 1e30f) ? v : 0.f;
}

// fast tanh: 1 - 2/(e^{2x}+1)
__device__ __forceinline__ float ftanh(float a) {
    float e = __expf(2.f * a);
    return 1.f - 2.f * __builtin_amdgcn_rcpf(e + 1.f);
}

__device__ __forceinline__ float ldf(const void* p, int i, int f32) {
    return f32 ? ((const float*)p)[i] : b2f(((const bf16*)p)[i]);
}
__device__ __forceinline__ void stf(void* p, int i, float v, int f32) {
    if (f32) ((float*)p)[i] = v;
    else ((bf16*)p)[i] = f2b(v);
}

__device__ __forceinline__ int clampi(int v, int hi) {
    return v < 0 ? 0 : (v >= hi ? hi - 1 : v);
}
__device__ __forceinline__ int idx_at(const int* p, int i, int is64) {
    return p[is64 ? (2 * i) : i];
}

__device__ __forceinline__ unsigned short bfbits(float v) {
    bf16 h = f2b(v);
    return *(unsigned short*)&h;
}
__device__ __forceinline__ unsigned int packbf2(float a, float b) {
    return (unsigned int)bfbits(a) | ((unsigned int)bfbits(b) << 16);
}
__device__ __forceinline__ float bflo(unsigned int u) { return __uint_as_float(u << 16); }
__device__ __forceinline__ float bfhi(unsigned int u) { return __uint_as_float(u & 0xffff0000u); }

__device__ __forceinline__ float xorReduce16(float v) {
    v += __shfl_xor(v, 1, 64);
    v += __shfl_xor(v, 2, 64);
    v += __shfl_xor(v, 4, 64);
    v += __shfl_xor(v, 8, 64);
    return v;
}
__device__ __forceinline__ float waveMax(float v) {
#pragma unroll
    for (int o = 1; o < 64; o <<= 1) v = fmaxf(v, __shfl_xor(v, o, 64));
    return v;
}
__device__ __forceinline__ float waveSum(float v) {
#pragma unroll
    for (int o = 1; o < 64; o <<= 1) v += __shfl_xor(v, o, 64);
    return v;
}

// 8-wide dot of W[row][col..col+8) with vec[0..8); W row stride = 2*HID
__device__ __forceinline__ float dot8(const void* W, int row, int col, int f32,
                                      const float* vec) {
    float s;
    if (f32) {
        const float* p = (const float*)W + (size_t)row * 2 * HID + col;
        float4 a = *(const float4*)p;
        float4 b = *(const float4*)(p + 4);
        s = a.x * vec[0] + a.y * vec[1] + a.z * vec[2] + a.w * vec[3]
          + b.x * vec[4] + b.y * vec[5] + b.z * vec[6] + b.w * vec[7];
    } else {
        short8 v = *(const short8*)((const bf16*)W + (size_t)row * 2 * HID + col);
        s = 0.f;
#pragma unroll
        for (int i = 0; i < 8; ++i) {
            unsigned int u = ((unsigned int)(unsigned short)v[i]) << 16;
            s += __uint_as_float(u) * vec[i];
        }
    }
    return s;
}

// ---------------------------------------------------------------- consolidated dtype detect
struct DetectArr {
    const void* p[16];
    int sz[16];
    int kind[16];
};

__global__ void detect_all(DetectArr d, int* __restrict__ flags) {
    int b = blockIdx.x;
    int t = threadIdx.x;
    if (d.kind[b] == 1) {
        // int64 detect: wave-parallel over the 64 sampled high words
        if (t < 64) {
            const int* q = (const int*)d.p[b];
            int o = q[2 * t + 1];
            unsigned long long bm = __ballot(o != 0);
            if (t == 0) flags[b] = (bm == 0ull) ? 1 : 0;
        }
        return;
    }
    __shared__ int sb[256], sf[256];
    const unsigned int* w = (const unsigned int*)d.p[b];
    int K = d.sz[b] >> 1;
    if (K > 4096) K = 4096;
    int bv = 0, fv = 0;
    for (int i = t; i < K; i += 256) {
        unsigned int x = w[i];
        unsigned int lo = x & 0xFFFFu, hi = x >> 16;
        if (lo == 0u) {
            if (hi) fv++;
        } else {
            unsigned int e = (lo >> 7) & 0xFFu;
            if (e >= 90u && e <= 160u) bv++;
            else fv++;
        }
    }
    sb[t] = bv; sf[t] = fv;
    __syncthreads();
    for (int o = 128; o > 0; o >>= 1) {
        if (t < o) { sb[t] += sb[t + o]; sf[t] += sf[t + o]; }
        __syncthreads();
    }
    if (t == 0) flags[b] = (sf[0] > sb[0]) ? 1 : 0;
}

// ---------------------------------------------------------------- BatchNorm: stats (1 block/column)
__global__ void bn_stats(const void* __restrict__ r, const int* __restrict__ flags,
                         float* __restrict__ stats) {
    __shared__ float sb[256], sq[256];
    const int fr = flags[1];
    int h = blockIdx.x;
    int t = threadIdx.x;
    float s = 0.f, ss = 0.f;
    for (int i = t; i < NR; i += 256) {
        float v = ldf(r, i * HID + h, fr);
        s += v; ss += v * v;
    }
    sb[t] = s; sq[t] = ss;
    __syncthreads();
    for (int o = 128; o > 0; o >>= 1) {
        if (t < o) { sb[t] += sb[t + o]; sq[t] += sq[t + o]; }
        __syncthreads();
    }
    if (t == 0) {
        float mu = sb[0] / NR;
        float var = sq[0] / NR - mu * mu;
        if (var < 0.f) var = 0.f;
        stats[h] = mu;
        stats[HID + h] = rsqrtf(var + 1e-5f);
    }
}

// ---------------------------------------------------------------- BatchNorm: apply (element-parallel)
__global__ void bn_apply(const void* __restrict__ r, const void* __restrict__ gamma,
                         const void* __restrict__ beta, const int* __restrict__ flags,
                         const float* __restrict__ stats,
                         float* __restrict__ rnorm, void* __restrict__ out_base) {
    const int fr = flags[1], fg = flags[14], fb = flags[15], fo = flags[0];
    int i = blockIdx.x * 256 + threadIdx.x;
    if (i >= NR * HID) return;
    int h = i & 127;
    float v = san((ldf(r, i, fr) - stats[h]) * stats[HID + h] * ldf(gamma, h, fg)
                  + ldf(beta, h, fb));
    rnorm[i] = v;
    stf(out_base, NN * HID + i, v, fo);
}

// ---------------------------------------------------------------- edge-constant vectors
// block 0: cmatt = Wmatt[:,128:] @ qc + bmatt ; block 1: cxatt = Wxatt[:,128:] @ fq + bxatt
// k-dim split across 2 thread groups, 8-wide vector loads, LDS reduce.
__global__ void precomp_kernel(const void* __restrict__ Wmatt, const void* __restrict__ bmatt,
                               const void* __restrict__ qc,
                               const void* __restrict__ Wxatt, const void* __restrict__ bxatt,
                               const void* __restrict__ fq, const int* __restrict__ flags,
                               float* __restrict__ cmatt, float* __restrict__ cxatt) {
    __shared__ float vs[HID];
    __shared__ float part[256];
    const void* W    = blockIdx.x ? Wxatt : Wmatt;
    const void* bias = blockIdx.x ? bxatt : bmatt;
    const void* vsrc = blockIdx.x ? fq : qc;
    float* out       = blockIdx.x ? cxatt : cmatt;
    const int fW = flags[blockIdx.x ? 11 : 8];
    const int fb = flags[blockIdx.x ? 12 : 9];
    const int fv = flags[blockIdx.x ? 3 : 2];
    int t = threadIdx.x;
    if (t < HID) vs[t] = ldf(vsrc, t, fv);
    __syncthreads();
    int h = t & 127, ks = t >> 7;        // ks in {0,1}: k-half
    float a = 0.f;
#pragma unroll
    for (int i = 0; i < 8; ++i)
        a += dot8(W, h, HID + ks * 64 + i * 8, fW, &vs[ks * 64 + i * 8]);
    part[t] = a;
    __syncthreads();
    if (t < HID) out[h] = san(part[h] + part[h + 128] + ldf(bias, h, fb));
}

// ---------------------------------------------------------------- Rmb[rel,h] (bf16), 2 rels/block
__global__ void rm_kernel(const void* __restrict__ Wmess, const void* __restrict__ bmess,
                          const int* __restrict__ flags,
                          const float* __restrict__ rnorm, bf16* __restrict__ Rmb) {
    __shared__ float rl[2][HID];
    const int fW = flags[6], fb = flags[7];
    int t = threadIdx.x;
    int sub = t >> 7, h = t & 127;
    int rel = blockIdx.x * 2 + sub;
    rl[sub][h] = rnorm[rel * HID + h];
    __syncthreads();
    float a = ldf(bmess, h, fb);
#pragma unroll
    for (int i = 0; i < 16; ++i)
        a += dot8(Wmess, h, HID + i * 8, fW, &rl[sub][i * 8]);
    Rmb[rel * HID + h] = f2b(san(a));
}

// ================================================================ MFMA kernels
#define MLDA 136

__device__ __forceinline__ short8 load_bfrag(const void* W, int n, int k0, int f32) {
    short8 b;
    if (f32) {
        const float* Wf = (const float*)W + (size_t)n * 2 * HID + k0;
        float4 u0 = *(const float4*)Wf;
        float4 u1 = *(const float4*)(Wf + 4);
        b[0] = (short)bfbits(u0.x); b[1] = (short)bfbits(u0.y);
        b[2] = (short)bfbits(u0.z); b[3] = (short)bfbits(u0.w);
        b[4] = (short)bfbits(u1.x); b[5] = (short)bfbits(u1.y);
        b[6] = (short)bfbits(u1.z); b[7] = (short)bfbits(u1.w);
    } else {
        b = *(const short8*)((const bf16*)W + (size_t)n * 2 * HID + k0);
    }
    return b;
}

// ---------------------------------------------------------------- Xm = x @ Wmess[:, :128]^T (1 tile/block)
__global__ __launch_bounds__(256, 4) void xm_mfma(const void* __restrict__ x,
                                                  const void* __restrict__ Wmess,
                                                  const int* __restrict__ flags,
                                                  bf16* __restrict__ Xmb) {
    __shared__ short ml[64 * MLDA];
    const int fx = flags[0], fW = flags[6];
    int tid = threadIdx.x;
    int l = tid & 63, w = tid >> 6;
    int quad = l >> 4, lo16 = l & 15;
    int nbase = w * 32;
    short8 bfr[2][4];
#pragma unroll
    for (int nt = 0; nt < 2; ++nt)
#pragma unroll
        for (int kk = 0; kk < 4; ++kk)
            bfr[nt][kk] = load_bfrag(Wmess, nbase + nt * 16 + lo16, kk * 32 + quad * 8, fW);

    const int ntiles = (NN + 63) / 64;
    for (int tile = blockIdx.x; tile < ntiles; tile += gridDim.x) {
        __syncthreads();
#pragma unroll
        for (int p = 0; p < 8; ++p) {
            int rl_ = p * 8 + (tid >> 5);
            int node = clampi(tile * 64 + rl_, NN);
            int k4 = (tid & 31) * 4;
            unsigned int o0, o1;
            if (fx) {
                float4 v = *(const float4*)((const float*)x + (size_t)node * HID + k4);
                o0 = packbf2(v.x, v.y);
                o1 = packbf2(v.z, v.w);
            } else {
                uint2 u = *(const uint2*)((const bf16*)x + (size_t)node * HID + k4);
                o0 = u.x; o1 = u.y;
            }
            unsigned int* dst = (unsigned int*)&ml[rl_ * MLDA + k4];
            dst[0] = o0; dst[1] = o1;
        }
        __syncthreads();
        float4_ acc[4][2];
#pragma unroll
        for (int mt = 0; mt < 4; ++mt)
#pragma unroll
            for (int nt = 0; nt < 2; ++nt)
                acc[mt][nt] = (float4_){0.f, 0.f, 0.f, 0.f};
#pragma unroll
        for (int kk = 0; kk < 4; ++kk) {
            short8 a[4];
#pragma unroll
            for (int mt = 0; mt < 4; ++mt)
                a[mt] = *(const short8*)&ml[(mt * 16 + lo16) * MLDA + kk * 32 + quad * 8];
#pragma unroll
            for (int mt = 0; mt < 4; ++mt)
#pragma unroll
                for (int nt = 0; nt < 2; ++nt)
                    acc[mt][nt] = __builtin_amdgcn_mfma_f32_16x16x32_bf16(
                        a[mt], bfr[nt][kk], acc[mt][nt], 0, 0, 0);
        }
#pragma unroll
        for (int mt = 0; mt < 4; ++mt)
#pragma unroll
            for (int nt = 0; nt < 2; ++nt)
#pragma unroll
                for (int r = 0; r < 4; ++r) {
                    int node = tile * 64 + mt * 16 + quad * 4 + r;
                    if (node < NN)
                        Xmb[node * HID + nbase + nt * 16 + lo16] = f2b(san(acc[mt][nt][r]));
                }
    }
}

// ---------------------------------------------------------------- edge logits: CSR-slot order
// 6 blocks/CU verified optimal TWICE (R2 tail-order, R11 octant-order: 8/CU re-creates
// L2 thrash both times — in-flight tile streams + write-allocate scale with block count).
// All structural alternatives refuted with counters: fusion (R1), head-order (R4: 4B
// scattered-write RMW), octant-XCD pinning (R10: -66MB FETCH but time-neutral — kernel
// sits at a VALU(48%)+latency equilibrium), messT materialization (R8: write volume >
// gather savings). This two-pass redundant-gather structure is the measured floor.
__global__ __launch_bounds__(256, 6) void edge_coeff_mfma(
        const bf16* __restrict__ Xmb, const bf16* __restrict__ Rmb,
        const void* __restrict__ Wmatt, const float* __restrict__ cmatt,
        const void* __restrict__ maw, const unsigned int* __restrict__ hrcsr,
        const int* __restrict__ flags, float* __restrict__ ccsr) {
    __shared__ short ml[64 * MLDA];
    __shared__ float swave[4][64];
    const int fWm = flags[8], fmw = flags[10];
    int tid = threadIdx.x;
    int l = tid & 63, w = tid >> 6;
    int quad = l >> 4, lo16 = l & 15;
    int nbase = w * 32;
    short8 bfr[2][4];
#pragma unroll
    for (int nt = 0; nt < 2; ++nt)
#pragma unroll
        for (int kk = 0; kk < 4; ++kk)
            bfr[nt][kk] = load_bfrag(Wmatt, nbase + nt * 16 + lo16, kk * 32 + quad * 8, fWm);

    int n0 = nbase + lo16, n1 = n0 + 16;
    float c0 = cmatt[n0], c1 = cmatt[n1];
    float w0 = ldf(maw, n0, fmw), w1 = ldf(maw, n1, fmw);

    const int ntiles = (NE + 63) / 64;
    const int seg = tid & 15;
    const int rowsub = tid >> 4;
    for (int T = blockIdx.x; T < ntiles; T += gridDim.x) {
        __syncthreads();
#pragma unroll
        for (int p = 0; p < 4; ++p) {
            int el = p * 16 + rowsub;
            int slot = T * 64 + el;
            unsigned int hr = hrcsr[slot < NE ? slot : NE - 1];
            int head = hr & 0xffffu, rel = hr >> 16;
            int k8 = seg * 8;
            uint4 xv = *(const uint4*)&Xmb[head * HID + k8];
            uint4 rv = *(const uint4*)&Rmb[rel * HID + k8];
            uint4 o;
            o.x = packbf2(ftanh(bflo(xv.x) + bflo(rv.x)), ftanh(bfhi(xv.x) + bfhi(rv.x)));
            o.y = packbf2(ftanh(bflo(xv.y) + bflo(rv.y)), ftanh(bfhi(xv.y) + bfhi(rv.y)));
            o.z = packbf2(ftanh(bflo(xv.z) + bflo(rv.z)), ftanh(bfhi(xv.z) + bfhi(rv.z)));
            o.w = packbf2(ftanh(bflo(xv.w) + bflo(rv.w)), ftanh(bfhi(xv.w) + bfhi(rv.w)));
            *(uint4*)&ml[el * MLDA + k8] = o;
        }
        __syncthreads();
        float4_ acc[4][2];
#pragma unroll
        for (int mt = 0; mt < 4; ++mt)
#pragma unroll
            for (int nt = 0; nt < 2; ++nt)
                acc[mt][nt] = (float4_){0.f, 0.f, 0.f, 0.f};
#pragma unroll
        for (int kk = 0; kk < 4; ++kk) {
            short8 a[4];
#pragma unroll
            for (int mt = 0; mt < 4; ++mt)
                a[mt] = *(const short8*)&ml[(mt * 16 + lo16) * MLDA + kk * 32 + quad * 8];
#pragma unroll
            for (int mt = 0; mt < 4; ++mt)
#pragma unroll
                for (int nt = 0; nt < 2; ++nt)
                    acc[mt][nt] = __builtin_amdgcn_mfma_f32_16x16x32_bf16(
                        a[mt], bfr[nt][kk], acc[mt][nt], 0, 0, 0);
        }
#pragma unroll
        for (int mt = 0; mt < 4; ++mt)
#pragma unroll
            for (int r = 0; r < 4; ++r) {
                float z0 = acc[mt][0][r] + c0;
                z0 = z0 > 0.f ? z0 : LRELU * z0;
                float z1 = acc[mt][1][r] + c1;
                z1 = z1 > 0.f ? z1 : LRELU * z1;
                float s = w0 * z0 + w1 * z1;
                s = xorReduce16(s);
                if (lo16 == 0) swave[w][mt * 16 + quad * 4 + r] = s;
            }
        __syncthreads();
        if (tid < 64) {
            int slot = T * 64 + tid;
            if (slot < NE)
                ccsr[slot] = san(swave[0][tid] + swave[1][tid] + swave[2][tid] + swave[3][tid]);
        }
    }
}

// ---------------------------------------------------------------- gate (1 tile/block)
__global__ __launch_bounds__(256, 4) void gate_mfma(
        const void* __restrict__ x, const bf16* __restrict__ smb,
        const void* __restrict__ Wxatt, const float* __restrict__ cxatt,
        const void* __restrict__ xaw, const int* __restrict__ flags,
        void* __restrict__ outx) {
    __shared__ short ml[64 * MLDA];
    __shared__ float swave[4][64];
    __shared__ float lgL[64];
    const int fx = flags[0], fWx = flags[11], fxw = flags[13], fo = flags[0];
    int tid = threadIdx.x;
    int l = tid & 63, w = tid >> 6;
    int quad = l >> 4, lo16 = l & 15;
    int nbase = w * 32;
    short8 bfr[2][4];
#pragma unroll
    for (int nt = 0; nt < 2; ++nt)
#pragma unroll
        for (int kk = 0; kk < 4; ++kk)
            bfr[nt][kk] = load_bfrag(Wxatt, nbase + nt * 16 + lo16, kk * 32 + quad * 8, fWx);

    int n0 = nbase + lo16, n1 = n0 + 16;
    float c0 = cxatt[n0], c1 = cxatt[n1];
    float w0 = ldf(xaw, n0, fxw), w1 = ldf(xaw, n1, fxw);

    const int ntiles = (NN + 31) / 32;
    for (int tile = blockIdx.x; tile < ntiles; tile += gridDim.x) {
        __syncthreads();
#pragma unroll
        for (int p = 0; p < 8; ++p) {
            int rl_ = p * 8 + (tid >> 5);
            int node = clampi(tile * 32 + (rl_ >> 1), NN);
            int k4 = (tid & 31) * 4;
            unsigned int o0, o1;
            if (rl_ & 1) {
                uint2 u = *(const uint2*)&smb[node * HID + k4];
                o0 = u.x; o1 = u.y;
            } else if (fx) {
                float4 v = *(const float4*)((const float*)x + (size_t)node * HID + k4);
                o0 = packbf2(v.x, v.y);
                o1 = packbf2(v.z, v.w);
            } else {
                uint2 u = *(const uint2*)((const bf16*)x + (size_t)node * HID + k4);
                o0 = u.x; o1 = u.y;
            }
            unsigned int* dst = (unsigned int*)&ml[rl_ * MLDA + k4];
            dst[0] = o0; dst[1] = o1;
        }
        __syncthreads();
        float4_ acc[4][2];
#pragma unroll
        for (int mt = 0; mt < 4; ++mt)
#pragma unroll
            for (int nt = 0; nt < 2; ++nt)
                acc[mt][nt] = (float4_){0.f, 0.f, 0.f, 0.f};
#pragma unroll
        for (int kk = 0; kk < 4; ++kk) {
            short8 a[4];
#pragma unroll
            for (int mt = 0; mt < 4; ++mt)
                a[mt] = *(const short8*)&ml[(mt * 16 + lo16) * MLDA + kk * 32 + quad * 8];
#pragma unroll
            for (int mt = 0; mt < 4; ++mt)
#pragma unroll
                for (int nt = 0; nt < 2; ++nt)
                    acc[mt][nt] = __builtin_amdgcn_mfma_f32_16x16x32_bf16(
                        a[mt], bfr[nt][kk], acc[mt][nt], 0, 0, 0);
        }
#pragma unroll
        for (int mt = 0; mt < 4; ++mt)
#pragma unroll
            for (int r = 0; r < 4; ++r) {
                float z0 = acc[mt][0][r] + c0;
                z0 = z0 > 0.f ? z0 : LRELU * z0;
                float z1 = acc[mt][1][r] + c1;
                z1 = z1 > 0.f ? z1 : LRELU * z1;
                float s = w0 * z0 + w1 * z1;
                s = xorReduce16(s);
                if (lo16 == 0) swave[w][mt * 16 + quad * 4 + r] = s;
            }
        __syncthreads();
        if (tid < 64)
            lgL[tid] = san(swave[0][tid] + swave[1][tid] + swave[2][tid] + swave[3][tid]);
        __syncthreads();
#pragma unroll
        for (int it = 0; it < 16; ++it) {
            int idx = tid + 256 * it;
            int nl = idx >> 7, h = idx & 127;
            int node = tile * 32 + nl;
            if (node < NN) {
                float g0 = lgL[2 * nl], g1 = lgL[2 * nl + 1];
                float mm = fmaxf(g0, g1);
                float e0 = __expf(g0 - mm), e1 = __expf(g1 - mm);
                float inv = __builtin_amdgcn_rcpf(e0 + e1);
                float xv = ldf(x, node * HID + h, fx);
                float sv = b2f(smb[node * HID + h]);
                stf(outx, node * HID + h, san((e0 * xv + e1 * sv) * inv), fo);
            }
        }
    }
}

// ---------------------------------------------------------------- CSR build
__global__ void count_kernel(const int* __restrict__ ei, const int* __restrict__ flags,
                             int* __restrict__ counts) {
    const int is64e = flags[4];
    for (int e = blockIdx.x * blockDim.x + threadIdx.x; e < NE; e += gridDim.x * blockDim.x) {
        int tail = clampi(idx_at(ei, NE + e, is64e), NN);
        atomicAdd(&counts[tail], 1);
    }
}

// 3-phase multi-block exclusive scan over counts[NN]
__global__ void scan_phase1(const int* __restrict__ counts, int* __restrict__ offs,
                            int* __restrict__ bsum) {
    __shared__ int buf[256];
    int t = threadIdx.x;
    int i = blockIdx.x * 256 + t;
    int v = (i < NN) ? counts[i] : 0;
    buf[t] = v;
    __syncthreads();
    for (int off = 1; off < 256; off <<= 1) {
        int add = (t >= off) ? buf[t - off] : 0;
        __syncthreads();
        buf[t] += add;
        __syncthreads();
    }
    if (i < NN) offs[i] = buf[t] - v;  // intra-block exclusive
    if (t == 255) bsum[blockIdx.x] = buf[255];
}

__global__ void scan_phase2(int* __restrict__ bsum, int* __restrict__ bexc) {
    __shared__ int buf[256];
    int t = threadIdx.x;
    int v = (t < SCAN_BLOCKS) ? bsum[t] : 0;
    buf[t] = v;
    __syncthreads();
    for (int off = 1; off < 256; off <<= 1) {
        int add = (t >= off) ? buf[t - off] : 0;
        __syncthreads();
        buf[t] += add;
        __syncthreads();
    }
    if (t < SCAN_BLOCKS) bexc[t] = buf[t] - v;
    if (t == 255) bexc[SCAN_BLOCKS] = buf[255];  // grand total
}

__global__ void scan_phase3(int* __restrict__ offs, int* __restrict__ cursor,
                            const int* __restrict__ bexc) {
    int i = blockIdx.x * 256 + threadIdx.x;
    if (i < NN) {
        int v = offs[i] + bexc[blockIdx.x];
        offs[i] = v;
        cursor[i] = v;
    }
    if (i == 0) offs[NN] = bexc[SCAN_BLOCKS];
}

__global__ void scatter_kernel(const int* __restrict__ ei, const int* __restrict__ ea,
                               const int* __restrict__ flags,
                               int* __restrict__ cursor, unsigned int* __restrict__ hrcsr) {
    const int is64e = flags[4], is64a = flags[5];
    for (int e = blockIdx.x * blockDim.x + threadIdx.x; e < NE; e += gridDim.x * blockDim.x) {
        int tail = clampi(idx_at(ei, NE + e, is64e), NN);
        int head = clampi(idx_at(ei, e, is64e), NN);
        int rel = clampi(idx_at(ea, e, is64a), NR);
        int p = atomicAdd(&cursor[tail], 1);
        if (p >= 0 && p < NE)
            hrcsr[p] = (unsigned int)head | ((unsigned int)rel << 16);
    }
}

// ---------------------------------------------------------------- node softmax + aggregation
__global__ __launch_bounds__(256, 8) void node_aggr_kernel(
        const bf16* __restrict__ Xmb, const bf16* __restrict__ Rmb,
        const int* __restrict__ offs, const unsigned int* __restrict__ hrcsr,
        const float* __restrict__ ccsr, bf16* __restrict__ smb) {
    int tid = threadIdx.x;
    int sub = tid >> 6;
    int lane = tid & 63;
    int node = blockIdx.x * 4 + sub;
    if (node >= NN) return;
    int s = offs[node], en = offs[node + 1];

    float m = -INFINITY;
    for (int i = s + lane; i < en; i += 64) m = fmaxf(m, ccsr[i]);
    m = waveMax(m);
    float lsum = 0.f;
    for (int i = s + lane; i < en; i += 64) lsum += __expf(ccsr[i] - m);
    lsum = waveSum(lsum);
    float inv = 1.f / (lsum + 1e-16f);

    const int col = lane * 2;
    float acc0 = 0.f, acc1 = 0.f;
    int i = s;
    for (; i + 2 <= en; i += 2) {
        unsigned int hr0 = hrcsr[i], hr1 = hrcsr[i + 1];
        float wg0 = __expf(ccsr[i] - m), wg1 = __expf(ccsr[i + 1] - m);
        unsigned int xv0 = *(const unsigned int*)&Xmb[(hr0 & 0xffffu) * HID + col];
        unsigned int rv0 = *(const unsigned int*)&Rmb[(hr0 >> 16) * HID + col];
        unsigned int xv1 = *(const unsigned int*)&Xmb[(hr1 & 0xffffu) * HID + col];
        unsigned int rv1 = *(const unsigned int*)&Rmb[(hr1 >> 16) * HID + col];
        acc0 += wg0 * ftanh(bflo(xv0) + bflo(rv0)) + wg1 * ftanh(bflo(xv1) + bflo(rv1));
        acc1 += wg0 * ftanh(bfhi(xv0) + bfhi(rv0)) + wg1 * ftanh(bfhi(xv1) + bfhi(rv1));
    }
    if (i < en) {
        unsigned int hr0 = hrcsr[i];
        float wg0 = __expf(ccsr[i] - m);
        unsigned int xv0 = *(const unsigned int*)&Xmb[(hr0 & 0xffffu) * HID + col];
        unsigned int rv0 = *(const unsigned int*)&Rmb[(hr0 >> 16) * HID + col];
        acc0 += wg0 * ftanh(bflo(xv0) + bflo(rv0));
        acc1 += wg0 * ftanh(bfhi(xv0) + bfhi(rv0));
    }
    *(unsigned int*)&smb[node * HID + col] = packbf2(san(acc0 * inv), san(acc1 * inv));
}

extern "C" void kernel_launch(void* const* d_in, const int* in_sizes, int n_in,
                              void* d_out, int out_size, void* d_ws, size_t ws_size,
                              hipStream_t stream) {
    const void* x     = d_in[0];
    const void* r     = d_in[1];
    const void* qc    = d_in[2];
    const void* fq    = d_in[3];
    const int*  ei    = (const int*)d_in[4];
    const int*  ea    = (const int*)d_in[5];
    const void* Wmess = d_in[6];
    const void* bmess = d_in[7];
    const void* Wmatt = d_in[8];
    const void* bmatt = d_in[9];
    const void* maw   = d_in[10];
    const void* Wxatt = d_in[11];
    const void* bxatt = d_in[12];
    const void* xaw   = d_in[13];
    const void* gamma = d_in[14];
    const void* beta  = d_in[15];

    int*          flags  = (int*)d_ws;                       // 16
    int*          counts = flags + 16;                       // NN
    int*          offs   = counts + NN;                      // NN+1
    int*          cursor = offs + NN + 1;                    // NN (+3 pad)
    int*          bsum   = cursor + NN + 3;                  // 256
    int*          bexc   = bsum + 256;                       // 256+1 (+3 pad)
    unsigned int* hrcsr  = (unsigned int*)(bexc + 260);      // NE
    float*        ccsr   = (float*)(hrcsr + NE);             // NE
    float*        rnorm  = ccsr + NE;                        // NR*HID
    float*        stats  = rnorm + (size_t)NR * HID;         // 2*HID
    float*        cmatt  = stats + 2 * HID;                  // HID
    float*        cxatt  = cmatt + HID;                      // HID
    bf16*         Rmb    = (bf16*)(cxatt + HID);             // NR*HID
    bf16*         Xmb    = Rmb + (size_t)NR * HID;           // NN*HID
    bf16*         smb    = Xmb + (size_t)NN * HID;           // NN*HID

    hipMemsetAsync(counts, 0, NN * sizeof(int), stream);

    DetectArr da;
    const void* ps[16] = {x, r, qc, fq, ei, ea, Wmess, bmess, Wmatt, bmatt, maw,
                          Wxatt, bxatt, xaw, gamma, beta};
    int szs[16] = {NN * HID, NR * HID, HID, HID, 2 * NE, NE, 2 * HID * HID, HID,
                   2 * HID * HID, HID, HID, 2 * HID * HID, HID, HID, HID, HID};
    for (int i = 0; i < 16; ++i) {
        da.p[i] = ps[i];
        da.sz[i] = szs[i];
        da.kind[i] = (i == 4 || i == 5) ? 1 : 0;
    }
    detect_all<<<16, 256, 0, stream>>>(da, flags);

    bn_stats<<<HID, 256, 0, stream>>>(r, flags, stats);
    bn_apply<<<(NR * HID + 255) / 256, 256, 0, stream>>>(r, gamma, beta, flags, stats,
                                                         rnorm, d_out);
    precomp_kernel<<<2, 256, 0, stream>>>(Wmatt, bmatt, qc, Wxatt, bxatt, fq, flags,
                                          cmatt, cxatt);
    rm_kernel<<<NR / 2, 256, 0, stream>>>(Wmess, bmess, flags, rnorm, Rmb);
    xm_mfma<<<782, 256, 0, stream>>>(x, Wmess, flags, Xmb);
    count_kernel<<<1024, 256, 0, stream>>>(ei, flags, counts);
    scan_phase1<<<SCAN_BLOCKS, 256, 0, stream>>>(counts, offs, bsum);
    scan_phase2<<<1, 256, 0, stream>>>(bsum, bexc);
    scan_phase3<<<SCAN_BLOCKS, 256, 0, stream>>>(offs, cursor, bexc);
    scatter_kernel<<<1024, 256, 0, stream>>>(ei, ea, flags, cursor, hrcsr);
    edge_coeff_mfma<<<1536, 256, 0, stream>>>(Xmb, Rmb, Wmatt, cmatt, maw, hrcsr, flags,
                                              ccsr);
    node_aggr_kernel<<<(NN + 3) / 4, 256, 0, stream>>>(Xmb, Rmb, offs, hrcsr, ccsr, smb);
    gate_mfma<<<1563, 256, 0, stream>>>(x, smb, Wxatt, cxatt, xaw, flags, d_out);
}